// Round 7
// baseline (4296.000 us; speedup 1.0000x reference)
//
#include <hip/hip_runtime.h>

typedef __bf16 bf16x8 __attribute__((ext_vector_type(8)));
typedef float f32x4 __attribute__((ext_vector_type(4)));
typedef unsigned u32x4 __attribute__((ext_vector_type(4)));
typedef unsigned short u16;

constexpr int T = 256, B = 64, D = 512, H = 1024;
constexpr int G4 = 4 * H;
constexpr int NBLK = 256;   // 2 layers x 2 batch-halves x 64 col-blocks (1/CU)
constexpr int NTHR = 256;   // 4 waves; wave = one K-quarter, all 4 gates
constexpr int BS = 32;      // batches per block
constexpr int MT = 2;       // 16-row MFMA tiles per block

__device__ __forceinline__ u16 f2bf(float f) {
  unsigned u = __builtin_bit_cast(unsigned, f);
  u += 0x7fffu + ((u >> 16) & 1u);
  return (u16)(u >> 16);
}

__device__ __forceinline__ f32x4 mfma16(bf16x8 a, bf16x8 b, f32x4 c) {
  return __builtin_amdgcn_mfma_f32_16x16x32_bf16(a, b, c, 0, 0, 0);
}

__device__ __forceinline__ float sigm(float x) { return 1.f / (1.f + expf(-x)); }

__device__ __forceinline__ int ldflag(const int* f, int i) {
  return __hip_atomic_load(&f[i], __ATOMIC_RELAXED, __HIP_MEMORY_SCOPE_AGENT);
}

// LLC-direct poll of one u32 (agent-scope atomic load bypasses L1/L2 -> sees
// write-through producer stores). Spins until nonzero (zero-escape encoding
// guarantees every written word is nonzero).
__device__ __forceinline__ unsigned poll_u32(const unsigned* p) {
  unsigned v = __hip_atomic_load(p, __ATOMIC_RELAXED, __HIP_MEMORY_SCOPE_AGENT);
  while (v == 0u) {
    __builtin_amdgcn_s_sleep(1);
    v = __hip_atomic_load(p, __ATOMIC_RELAXED, __HIP_MEMORY_SCOPE_AGENT);
  }
  return v;
}

// ---------------- prep kernels ----------------
__global__ void cvt_bf16(const float* __restrict__ src, u16* __restrict__ dst, int n4) {
  int i = blockIdx.x * blockDim.x + threadIdx.x;
  int st = gridDim.x * blockDim.x;
  for (; i < n4; i += st) {
    float4 v = reinterpret_cast<const float4*>(src)[i];
    ushort4 o;
    o.x = f2bf(v.x); o.y = f2bf(v.y); o.z = f2bf(v.z); o.w = f2bf(v.w);
    reinterpret_cast<ushort4*>(dst)[i] = o;
  }
}

__global__ void zero_u4(uint4* __restrict__ dst, int n) {
  int i = blockIdx.x * blockDim.x + threadIdx.x;
  int st = gridDim.x * blockDim.x;
  const uint4 z = make_uint4(0u, 0u, 0u, 0u);
  for (; i < n; i += st) dst[i] = z;
}

__global__ void init_state(const float* __restrict__ h0,
                           u16* __restrict__ xs1, u16* __restrict__ h1buf,
                           const float* __restrict__ bih0, const float* __restrict__ bhh0,
                           const float* __restrict__ bih1, const float* __restrict__ bhh1,
                           float* __restrict__ bias0, float* __restrict__ bias1,
                           int* __restrict__ flags) {
  int i = blockIdx.x * blockDim.x + threadIdx.x;
  if (i < NBLK) flags[i] = 0;              // fallback-mode flags (replay-safe reset)
  if (i < 2 * B * H) {
    int l = i / (B * H), rem = i % (B * H);
    int b = rem / H, k = rem % H;
    u16 v = f2bf(h0[(size_t)b * 2 * H + (size_t)l * H + k]);
    if (v == 0) v = 1;   // zero-escape: written bf16 is never 0x0000 (err ~1e-40)
    if (l == 0) xs1[(size_t)b * H + k] = v;   // slot 0 = initial h for layer0
    else        h1buf[(size_t)b * H + k] = v; // slot 0 = initial h for layer1
  }
  if (i < G4) {
    bias0[i] = bih0[i] + bhh0[i];
    bias1[i] = bih1[i] + bhh1[i];
  }
}

// ---------------- persistent pipelined LSTM ----------------
// Logical block lb = g*64 + c, g = L*2+half; hw blockIdx = 8*(c>>1) + 2g + (c&1)
// -> each group's 64 blocks land on 2 XCDs (L2 sharing; FETCH 451->144 MB).
// Weights AGPR-pinned; 1 wave/SIMD -> program order = critical path.
//
// Full mode: NO flags, NO producer drain — the DATA is the ready signal.
//   - all h-history slabs pre-zeroed each launch; published words zero-escaped
//     (u32 0 -> 1 = one bf16 denormal, error ~1e-40)
//   - consumers bulk-load h with plain cached loads (L2-dedup kept), then
//     verify every u32 != 0; zero words (stragglers / stale-zero L2 lines)
//     are re-polled via agent atomic loads that read the LLC directly
//   - producer publish stores just flow; red LDS is parity-double-buffered so
//     the tail barrier disappears (one mid-step __syncthreads remains, whose
//     auto vmcnt(0) only ever sees long-completed ops)
// Chain per step: publish-store propagation + data-poll detect (~1-1.5 LLC RT)
// vs R6's drain + flag post + flag poll + load (~3 RT).
// Fallback (small ws): R6 scheme — ring slots + flags + acquire fence.
template <int L>
__device__ __forceinline__ void run_layer(
    const u16* __restrict__ xin, const u16* __restrict__ wx, const u16* __restrict__ wh,
    const float* __restrict__ bias, u16* __restrict__ xs1, u16* __restrict__ h1b,
    const float* __restrict__ c0, const int* __restrict__ reset,
    float* __restrict__ out, int* __restrict__ flags, int half, int col0, int lb,
    f32x4* __restrict__ red, unsigned* __restrict__ rbits, float* __restrict__ lbias,
    const int s1mask, const int h1mask, const int full) {
  constexpr int KX   = L ? H : D;
  constexpr int NCX  = KX / 32;
  constexpr int NCXW = NCX / 4;        // x chunks per wave (4 or 8)
  constexpr int NHW  = (H / 32) / 4;   // h chunks per wave (8)
  constexpr int NCW  = NCXW + NHW;
  const size_t BH = (size_t)B * H;
  const size_t OUT_HN = (size_t)T * BH;
  const size_t OUT_CN = OUT_HN + 2 * BH;

  const int tid  = threadIdx.x;
  const int ks   = tid >> 6;
  const int lane = tid & 63;
  const int q    = lane >> 4;
  const int ln   = lane & 15;

  // ---- one-time LDS prep
  for (int t = tid; t < T; t += NTHR) {
    unsigned v = 0;
#pragma unroll 8
    for (int i = 0; i < 32; ++i)
      v |= (unsigned)(reset[t * B + half * BS + i] & 1) << i;
    rbits[t] = v;
  }
  if (tid < 64) lbias[tid] = bias[(tid >> 4) * H + col0 + (tid & 15)];

  // ---- weights -> AGPR (pinned; VGPRs stay free for load pipelining)
  u32x4 wreg[4][NCW];
#pragma unroll
  for (int g = 0; g < 4; ++g)
#pragma unroll
    for (int cc = 0; cc < NCW; ++cc) {
      const bool isx = cc < NCXW;
      const int c = isx ? ks * NCXW + cc : ks * NHW + (cc - NCXW);
      const u16* W = isx ? wx : wh;
      const int stride = isx ? KX : H;
      const int kk = c * 32 + q * 8;
      wreg[g][cc] = *reinterpret_cast<const u32x4*>(
          W + (size_t)(g * H + col0 + ln) * stride + kk);
    }
#pragma unroll
  for (int g = 0; g < 4; ++g)
#pragma unroll
    for (int cc = 0; cc < NCW; ++cc)
      asm volatile("" : "+a"(wreg[g][cc]));

  // ---- cell state: thread (tid<128) owns batches b0l..b0l+3, col cl
  const int b0l = (tid >> 4) * 4;
  const int cl  = col0 + (tid & 15);
  float creg[4] = {0.f, 0.f, 0.f, 0.f};
  if (tid < 128)
#pragma unroll
    for (int r = 0; r < 4; ++r)
      creg[r] = c0[(size_t)(half * BS + b0l + r) * 2 * H + (size_t)L * H + cl];

  __syncthreads();
  float bval[4];
#pragma unroll
  for (int g = 0; g < 4; ++g) bval[g] = lbias[g * 16 + (tid & 15)];

  float hv[4] = {0.f, 0.f, 0.f, 0.f};

  // persistent x prefetch regs
  uint4 xf[NCXW][MT];
  auto load_xfrags = [&](const u16* xsrc) {
#pragma unroll
    for (int cc = 0; cc < NCXW; ++cc) {
      const int kk = (ks * NCXW + cc) * 32 + q * 8;
#pragma unroll
      for (int m = 0; m < MT; ++m)
        xf[cc][m] = *reinterpret_cast<const uint4*>(
            xsrc + (size_t)(half * BS + 16 * m + ln) * KX + kk);
    }
  };
  if (full && L == 0) load_xfrags(xin);   // t=0 prologue (static input)

  const u16* xsrc_prev = xs1;   // L1: slab xf was prefetched from (for verify)

  for (int s = 0; s <= T; ++s) {
    const bool active = (L == 0) ? (s < T) : (s >= 1);
    const int t = (L == 0) ? s : s - 1;
    if (active) {
      const u16* hsrc = (L == 0) ? xs1 + (size_t)(s & s1mask) * BH
                                 : h1b + (size_t)(t & h1mask) * BH;
      uint4 hf[NHW][MT];

      if (full) {
        // ---- bulk h loads (plain, cached -> L2 dedup) issued immediately
#pragma unroll
        for (int cc = 0; cc < NHW; ++cc) {
          const int kk = (ks * NHW + cc) * 32 + q * 8;
#pragma unroll
          for (int m = 0; m < MT; ++m)
            hf[cc][m] = *reinterpret_cast<const uint4*>(
                hsrc + (size_t)(half * BS + 16 * m + ln) * H + kk);
        }
        // ---- verify prefetched x (L1 only; covers stale/straggler words)
        if (L == 1) {
          unsigned mn = 0xffffffffu;
#pragma unroll
          for (int cc = 0; cc < NCXW; ++cc)
#pragma unroll
            for (int m = 0; m < MT; ++m) {
              mn = min(mn, min(min(xf[cc][m].x, xf[cc][m].y),
                               min(xf[cc][m].z, xf[cc][m].w)));
            }
          if (mn == 0u) {
#pragma unroll
            for (int cc = 0; cc < NCXW; ++cc)
#pragma unroll
              for (int m = 0; m < MT; ++m) {
                const unsigned* p = reinterpret_cast<const unsigned*>(
                    xsrc_prev + (size_t)(half * BS + 16 * m + ln) * KX +
                    (ks * NCXW + cc) * 32 + q * 8);
                if (xf[cc][m].x == 0u) xf[cc][m].x = poll_u32(p + 0);
                if (xf[cc][m].y == 0u) xf[cc][m].y = poll_u32(p + 1);
                if (xf[cc][m].z == 0u) xf[cc][m].z = poll_u32(p + 2);
                if (xf[cc][m].w == 0u) xf[cc][m].w = poll_u32(p + 3);
              }
          }
        }
      } else {
        // fallback: full-grid flag poll + acquire fence, then load everything
        for (;;) {
          int a = ldflag(flags, lane),       b = ldflag(flags, 64 + lane);
          int c = ldflag(flags, 128 + lane), d = ldflag(flags, 192 + lane);
          int m1 = a < b ? a : b, m2 = c < d ? c : d;
          if ((m1 < m2 ? m1 : m2) >= s) break;
          __builtin_amdgcn_s_sleep(1);
        }
        __builtin_amdgcn_fence(__ATOMIC_ACQUIRE, "agent");   // buffer_inv
        asm volatile("" ::: "memory");
        load_xfrags((L == 0) ? xin + (size_t)t * B * D
                             : xs1 + (size_t)(s & s1mask) * BH);
#pragma unroll
        for (int cc = 0; cc < NHW; ++cc) {
          const int kk = (ks * NHW + cc) * 32 + q * 8;
#pragma unroll
          for (int m = 0; m < MT; ++m)
            hf[cc][m] = *reinterpret_cast<const uint4*>(
                hsrc + (size_t)(half * BS + 16 * m + ln) * H + kk);
        }
      }

      f32x4 acc[4][MT];
#pragma unroll
      for (int g = 0; g < 4; ++g)
#pragma unroll
        for (int m = 0; m < MT; ++m) acc[g][m] = (f32x4){0.f, 0.f, 0.f, 0.f};

      // ---- x MFMAs from prefetched regs (cover in-flight h loads)
#pragma unroll
      for (int cc = 0; cc < NCXW; ++cc)
#pragma unroll
        for (int g = 0; g < 4; ++g)
#pragma unroll
          for (int m = 0; m < MT; ++m)
            acc[g][m] = mfma16(__builtin_bit_cast(bf16x8, xf[cc][m]),
                               __builtin_bit_cast(bf16x8, wreg[g][cc]), acc[g][m]);

      // ---- verify h words (full mode): zero -> LLC-direct re-poll
      if (full) {
        unsigned mn = 0xffffffffu;
#pragma unroll
        for (int cc = 0; cc < NHW; ++cc)
#pragma unroll
          for (int m = 0; m < MT; ++m) {
            mn = min(mn, min(min(hf[cc][m].x, hf[cc][m].y),
                             min(hf[cc][m].z, hf[cc][m].w)));
          }
        if (mn == 0u) {
#pragma unroll
          for (int cc = 0; cc < NHW; ++cc)
#pragma unroll
            for (int m = 0; m < MT; ++m) {
              const unsigned* p = reinterpret_cast<const unsigned*>(
                  hsrc + (size_t)(half * BS + 16 * m + ln) * H +
                  (ks * NHW + cc) * 32 + q * 8);
              if (hf[cc][m].x == 0u) hf[cc][m].x = poll_u32(p + 0);
              if (hf[cc][m].y == 0u) hf[cc][m].y = poll_u32(p + 1);
              if (hf[cc][m].z == 0u) hf[cc][m].z = poll_u32(p + 2);
              if (hf[cc][m].w == 0u) hf[cc][m].w = poll_u32(p + 3);
            }
        }
      }

      // ---- h MFMAs (reset zeroes recurrent rows)
      const unsigned rw = rbits[t];
      const int rz0 = (int)((rw >> ln) & 1u);
      const int rz1 = (int)((rw >> (16 + ln)) & 1u);
      const uint4 zz = make_uint4(0u, 0u, 0u, 0u);
#pragma unroll
      for (int cc = 0; cc < NHW; ++cc) {
        const uint4 v0 = rz0 ? zz : hf[cc][0];
        const uint4 v1 = rz1 ? zz : hf[cc][1];
#pragma unroll
        for (int g = 0; g < 4; ++g) {
          acc[g][0] = mfma16(__builtin_bit_cast(bf16x8, v0),
                             __builtin_bit_cast(bf16x8, wreg[g][NCXW + cc]), acc[g][0]);
          acc[g][1] = mfma16(__builtin_bit_cast(bf16x8, v1),
                             __builtin_bit_cast(bf16x8, wreg[g][NCXW + cc]), acc[g][1]);
        }
      }

      // ---- dump partials: parity red buffer, conflict-free ds_write_b128
      f32x4* rbuf = red + (size_t)(s & 1) * (16 * 128);
#pragma unroll
      for (int g = 0; g < 4; ++g)
#pragma unroll
        for (int m = 0; m < MT; ++m)
          rbuf[(g * 4 + ks) * 128 + m * 64 + lane] = acc[g][m];
      __syncthreads();   // the ONE per-step rendezvous

      // ---- reduce + cell update
      if (tid < 128) {
        f32x4 gate[4];
#pragma unroll
        for (int g = 0; g < 4; ++g) {
          f32x4 sum = rbuf[(g * 4 + 0) * 128 + tid];
#pragma unroll
          for (int w = 1; w < 4; ++w) sum += rbuf[(g * 4 + w) * 128 + tid];
          gate[g] = sum + (f32x4){bval[g], bval[g], bval[g], bval[g]};
        }
        const unsigned rstw = rbits[t] >> b0l;
        u16 hb[4];
#pragma unroll
        for (int r = 0; r < 4; ++r) {
          float cp = ((rstw >> r) & 1u) ? 0.f : creg[r];
          float i_ = sigm(gate[0][r]);
          float f_ = sigm(gate[1][r]);
          float g_ = tanhf(gate[2][r]);
          float o_ = sigm(gate[3][r]);
          float cn = fmaf(f_, cp, i_ * g_);
          float hn = o_ * tanhf(cn);
          creg[r] = cn;
          hv[r] = hn;
          hb[r] = f2bf(hn);
        }
        if (s < T) {   // publish h: write-through agent stores, zero-escaped
          u16* hdst = (L == 0)
              ? xs1 + (size_t)((s + 1) & s1mask) * BH
              : h1b + (size_t)((t + 1) & h1mask) * BH;
#pragma unroll
          for (int r = 0; r < 4; ++r) {
            unsigned own = hb[r];
            unsigned oth = (unsigned)__shfl_xor((int)own, 1);
            unsigned pk = (tid & 1) ? ((oth & 0xffffu) | (own << 16))
                                    : (own | (oth << 16));
            if (pk == 0u) pk = 1u;   // zero-escape (one bf16 denormal)
            if ((r >> 1) == (tid & 1))
              __hip_atomic_store(
                  reinterpret_cast<unsigned*>(
                      hdst + (size_t)(half * BS + b0l + r) * H + (cl & ~1)),
                  pk, __ATOMIC_RELAXED, __HIP_MEMORY_SCOPE_AGENT);
          }
        }
        if (t == T - 1) {
#pragma unroll
          for (int r = 0; r < 4; ++r) {
            const size_t brow = (size_t)(half * BS + b0l + r);
            __builtin_nontemporal_store(
                hv[r], &out[OUT_HN + brow * 2 * H + (size_t)L * H + cl]);
            __builtin_nontemporal_store(
                creg[r], &out[OUT_CN + brow * 2 * H + (size_t)L * H + cl]);
            if (L == 1)
              __builtin_nontemporal_store(
                  hv[r], &out[(size_t)t * BH + brow * H + cl]);
          }
        }
      }
    }

    // ---- tail: NO barrier in full mode (publish stores just flow).
    // Deferred out rows (plain, L2-ack) + next-step x prefetch.
    if (s < T) {
      if (L == 1 && active && t < T - 1 && tid < 128) {
#pragma unroll
        for (int r = 0; r < 4; ++r)
          out[(size_t)t * BH + (size_t)(half * BS + b0l + r) * H + cl] = hv[r];
      }
      if (full) {
        if (L == 0) {
          if (s + 1 < T) load_xfrags(xin + (size_t)(s + 1) * B * D);
        } else {
          // x for step s+1 = xs1[s+1]; bulk-prefetch now, verify at next head
          xsrc_prev = xs1 + (size_t)((s + 1) & s1mask) * BH;
          load_xfrags(xsrc_prev);
        }
      } else {
        __syncthreads();   // fallback: drain all, then post block flag
        if (tid == 0)
          __hip_atomic_store(&flags[lb], s + 1,
                             __ATOMIC_RELAXED, __HIP_MEMORY_SCOPE_AGENT);
      }
    }
  }
}

__global__ void __launch_bounds__(NTHR, 1) lstm_seq(
    const u16* __restrict__ xin,
    const u16* __restrict__ wx0, const u16* __restrict__ wh0,
    const u16* __restrict__ wx1, const u16* __restrict__ wh1,
    const float* __restrict__ bias0, const float* __restrict__ bias1,
    u16* __restrict__ xs1, u16* __restrict__ h1b,
    const float* __restrict__ c0, const int* __restrict__ reset,
    float* __restrict__ out, int* __restrict__ flags,
    int s1mask, int h1mask, int full) {
  __shared__ f32x4 red[2 * 16 * 128];     // 64 KB partials, step-parity dbuf
  __shared__ unsigned rbits[T];           // packed reset bits (this half)
  __shared__ float lbias[64];
  // hw blockIdx -> (g, c): group g on XCDs {2g, 2g+1} (%8 round-robin heuristic)
  const int g    = (blockIdx.x & 7) >> 1;
  const int c    = ((blockIdx.x >> 3) << 1) | (blockIdx.x & 1);
  const int half = g & 1;
  const int col0 = c << 4;
  const int lb   = g * 64 + c;
  if ((g >> 1) == 0)
    run_layer<0>(xin, wx0, wh0, bias0, xs1, h1b, c0, reset, out, flags, half, col0, lb,
                 red, rbits, lbias, s1mask, h1mask, full);
  else
    run_layer<1>(nullptr, wx1, wh1, bias1, xs1, h1b, c0, reset, out, flags, half, col0, lb,
                 red, rbits, lbias, s1mask, h1mask, full);
}

extern "C" void kernel_launch(void* const* d_in, const int* in_sizes, int n_in,
                              void* d_out, int out_size, void* d_ws, size_t ws_size,
                              hipStream_t stream) {
  (void)in_sizes; (void)n_in; (void)out_size;
  const float* input = (const float*)d_in[0];
  const int*   reset = (const int*)d_in[1];
  const float* h0    = (const float*)d_in[2];
  const float* c0    = (const float*)d_in[3];
  const float* Wih0  = (const float*)d_in[4];
  const float* Whh0  = (const float*)d_in[5];
  const float* bih0  = (const float*)d_in[6];
  const float* bhh0  = (const float*)d_in[7];
  const float* Wih1  = (const float*)d_in[8];
  const float* Whh1  = (const float*)d_in[9];
  const float* bih1  = (const float*)d_in[10];
  const float* bhh1  = (const float*)d_in[11];
  float* out = (float*)d_out;
  char* ws = (char*)d_ws;

  const size_t SLOT = (size_t)B * H * 2;             // one [B][H] bf16 slab (128 KB)
  const size_t FIXED = (size_t)G4 * D * 2 + 3 * (size_t)G4 * H * 2
                     + (size_t)T * B * D * 2
                     + 2 * (size_t)G4 * 4 + 8192;
  const bool full = ws_size >= FIXED + 2 * (size_t)(T + 1) * SLOT + 65536;
  const int d0 = full ? (T + 1) : 4;
  const int d1 = full ? (T + 1) : 2;
  const int s1mask = full ? 511 : 3;
  const int h1mask = full ? 511 : 1;

  size_t off = 0;
  auto alloc = [&](size_t bytes) { size_t o = off; off += (bytes + 255) & ~(size_t)255; return o; };
  u16* wx0 = (u16*)(ws + alloc((size_t)G4 * D * 2));
  u16* wh0 = (u16*)(ws + alloc((size_t)G4 * H * 2));
  u16* wx1 = (u16*)(ws + alloc((size_t)G4 * H * 2));
  u16* wh1 = (u16*)(ws + alloc((size_t)G4 * H * 2));
  u16* xin = (u16*)(ws + alloc((size_t)T * B * D * 2));
  u16* xs1 = (u16*)(ws + alloc((size_t)d0 * SLOT));
  u16* h1b = (u16*)(ws + alloc((size_t)d1 * SLOT));
  float* pb0 = (float*)(ws + alloc((size_t)G4 * 4));
  float* pb1 = (float*)(ws + alloc((size_t)G4 * 4));
  int* flg = (int*)(ws + alloc(1024));

  cvt_bf16<<<1024, 256, 0, stream>>>(Wih0, wx0, G4 * D / 4);
  cvt_bf16<<<1024, 256, 0, stream>>>(Whh0, wh0, G4 * H / 4);
  cvt_bf16<<<1024, 256, 0, stream>>>(Wih1, wx1, G4 * H / 4);
  cvt_bf16<<<1024, 256, 0, stream>>>(Whh1, wh1, G4 * H / 4);
  cvt_bf16<<<2048, 256, 0, stream>>>(input, xin, T * B * D / 4);
  if (full) {
    // pre-zero slabs 1..T of both h histories (slot 0 written by init_state);
    // runs EVERY launch -> replay-safe (previous run's data wiped)
    const int n4 = (int)((size_t)T * B * H * 2 / 16);
    zero_u4<<<2048, 256, 0, stream>>>((uint4*)(xs1 + (size_t)B * H), n4);
    zero_u4<<<2048, 256, 0, stream>>>((uint4*)(h1b + (size_t)B * H), n4);
  }
  init_state<<<512, 256, 0, stream>>>(h0, xs1, h1b, bih0, bhh0, bih1, bhh1, pb0, pb1, flg);
  lstm_seq<<<NBLK, NTHR, 0, stream>>>(xin, wx0, wh0, wx1, wh1, pb0, pb1,
                                      xs1, h1b, c0, reset, out, flg,
                                      s1mask, h1mask, full ? 1 : 0);
}